// Round 5
// baseline (1519.557 us; speedup 1.0000x reference)
//
#include <hip/hip_runtime.h>

#define H 65
#define T_STEPS 1024

typedef _Float16 half_t;
typedef _Float16 half2_t __attribute__((ext_vector_type(2)));

// Guaranteed v_dot2_f32_f16
static __device__ __forceinline__ float dot2(half2_t a, half2_t b, float c) {
#if __has_builtin(__builtin_amdgcn_fdot2)
  return __builtin_amdgcn_fdot2(a, b, c, false);
#else
  float d;
  asm("v_dot2_f32_f16 %0, %1, %2, %3" : "=v"(d) : "v"(a), "v"(b), "v"(c));
  return d;
#endif
}

// Quad-lane permute via DPP. 0xB1=[1,0,3,2] (xor1), 0x4E=[2,3,0,1] (xor2)
template <int CTRL>
static __device__ __forceinline__ float qperm(float v) {
  int r = __builtin_amdgcn_update_dpp(0, __builtin_bit_cast(int, v), CTRL, 0xF, 0xF, true);
  return __builtin_bit_cast(float, r);
}

// ds_swizzle BitMode: offset = (xor<<10)|(or<<5)|and(0x1F)
template <int PAT>
static __device__ __forceinline__ float swz(float v) {
  int r = __builtin_amdgcn_ds_swizzle(__builtin_bit_cast(int, v), PAT);
  return __builtin_bit_cast(float, r);
}

#define LOG2E 1.44269504089f
static __device__ __forceinline__ float fast_sigm(float v) {
  float e = __builtin_amdgcn_exp2f(-LOG2E * v);
  return __builtin_amdgcn_rcpf(1.f + e);
}

// select [a,b,c,d][idx], branchless
static __device__ __forceinline__ float pick(int idx, float a, float b, float c, float d) {
  float lo = (idx & 1) ? b : a;
  float hi = (idx & 1) ? d : c;
  return (idx & 2) ? hi : lo;
}

// 256 blocks x 512 threads = exactly 1 block/CU; each block runs TWO batch
// rows (2b, 2b+1) in the SAME lanes (ILP doubling).
//
// Why this shape (r0-r4 evidence):
//  - 1024t workgroups: compiler always picks the 64-VGPR budget -> the
//    66-reg weight cache spills to scratch (r3/r4: 43-46MB scratch traffic,
//    ~45 dwords/lane reloaded every step). Attributes could not override.
//  - 512t + __launch_bounds__(512,2): proven 92-reg spill-free codegen (r1),
//    but two 512t blocks never co-resided -> two sequential grid rounds.
//  - Fix: one 512t block per CU, two rows per block. Weight registers are
//    SHARED between the rows (same weights), so doubling rows costs only
//    ~12 extra regs (2nd cell state / accumulators / operands): ~105 <= 128.
//    The second row's independent instruction stream fills the dependency
//    stalls that capped r1 at VALUBusy 46%.
//
// Quad scheme (per lane, both rows): quad = tid>>2 in [0,128) -> unit (l,j):
// quads 0..64 = (0,j), 65..127 = (1, j=0..62). kh=(tid>>1)&1 K-half,
// g0=tid&1 gate pair. DPP xor2 K-combine, xor1 gate-pair exchange.
// Missing units (l=1, j=63,64): EC path on wave 7 (both rows).
// x staging on wave 6 (both rows, distance-2 prefetch).
// h double-buffered in LDS by parity. Pipeline: L0 t=s, L1 t=s-1.
__global__ __launch_bounds__(512, 2) void lstm_fused(
    const float* __restrict__ x,
    const float* __restrict__ wih0, const float* __restrict__ whh0,
    const float* __restrict__ bih0, const float* __restrict__ bhh0,
    const float* __restrict__ wih1, const float* __restrict__ whh1,
    const float* __restrict__ bih1, const float* __restrict__ bhh1,
    const float* __restrict__ wlin, const float* __restrict__ blin,
    float* __restrict__ out)
{
  // xh[row][layer][parity][144]: 0..64 input part (x for L0, h0 for L1),
  // 65..71 zero pad, 72..136 recurrent h, 137..143 zero pad.
  __shared__ __align__(16) half_t xh[2][2][2][144];
  __shared__ float h1f[2][H];

  const int tid = threadIdx.x;

  const int quad = tid >> 2;
  const int l  = (quad >= 65) ? 1 : 0;
  const int j  = quad - 65 * l;
  const int kh = (tid >> 1) & 1;
  const int g0 = tid & 1;
  const bool gz = (g0 == 0);
  const float mreg = gz ? 2.f : 1.f;  // gate g0+2 is tanh (g~) iff g0==0
  const float msub = mreg - 1.f;

  // ---- regular weights: 2 gate-columns x K-half = 66 half2 VGPRs ----
  // (shared by BOTH rows this block processes)
  half2_t w[2][33];
  float hb[2];  // 0.5*bias; xor2 K-combine restores full bias
  {
    const float* wi = l ? wih1 : wih0;
    const float* wh = l ? whh1 : whh0;
    const float* bi = l ? bih1 : bih0;
    const float* bh = l ? bhh1 : bhh0;
#pragma unroll
    for (int cc = 0; cc < 2; ++cc) {
      const int row = (g0 + 2 * cc) * H + j;
      hb[cc] = 0.5f * (bi[row] + bh[row]);
      const float* src = (kh ? wh : wi) + row * H;
#pragma unroll
      for (int pp = 0; pp < 33; ++pp) {
        float e0 = src[2 * pp];
        float e1 = (2 * pp + 1 < H) ? src[2 * pp + 1] : 0.f;
        half2_t v = {(half_t)e0, (half_t)e1};
        w[cc][pp] = v;
      }
    }
  }

  // ---- EC: extra columns (l=1, j=63/64), on wave 7 (both rows) ----
  // w7 = tid-448; ec = w7>>3 in [0,8) -> column (gate=ec&3, j=63+(ec>>2));
  // ck = w7&7 chunk; side = ck>>2 (0=x-side,1=h-side); sck = ck&3.
  // Lane covers side pair-indices es = 9*sck + i (valid es<33; rest zeroed,
  // operand reads land in the zero pads -> contribute 0).
  const bool isW7 = (tid >= 448);
  const int  w7   = tid - 448;
  const int  ec   = w7 >> 3;
  const int  ck   = w7 & 7;
  const int  side = ck >> 2;
  const int  sck  = ck & 3;
  const int  ecoff = side * 144 + 36 * sck;  // byte offset within xh[r][1][p]
  half2_t ecw[9];
  float ecbias = 0.f;
  float cecA = 0.f, cecB = 0.f;
  if (isW7) {
    const int gec = ec & 3;
    const int jec = 63 + (ec >> 2);
    const int row = gec * H + jec;
    const float* src = (side ? whh1 : wih1) + row * H;
#pragma unroll
    for (int i = 0; i < 9; ++i) {
      int es = 9 * sck + i;
      float e0 = (es < 33) ? src[2 * es] : 0.f;
      float e1 = (es < 33 && 2 * es + 1 < H) ? src[2 * es + 1] : 0.f;
      half2_t v = {(half_t)e0, (half_t)e1};
      ecw[i] = v;
    }
    if (ck == 0) ecbias = bih1[row] + bhh1[row];
  } else {
#pragma unroll
    for (int i = 0; i < 9; ++i) {
      half2_t z = {(half_t)0.f, (half_t)0.f};
      ecw[i] = z;
    }
  }

  // ---- loaders: wave 6 stages BOTH rows' x (distance-2 pipeline) ----
  const bool isW6 = (tid >= 384) && (tid < 448);
  const int  u    = tid - 384;

  // ---- zero LDS (initial h,c=0; pads stay 0 forever) ----
  for (int i = tid; i < 2 * 2 * 2 * 144; i += 512) ((half_t*)xh)[i] = (half_t)0.f;
  __syncthreads();

  const float* xrowA = x + (size_t)(2 * blockIdx.x)     * (size_t)(T_STEPS * H);
  const float* xrowB = x + (size_t)(2 * blockIdx.x + 1) * (size_t)(T_STEPS * H);
  float nA = 0.f, nA64 = 0.f, nB = 0.f, nB64 = 0.f;
  if (isW6) {
    xh[0][0][0][u] = (half_t)xrowA[u];
    xh[1][0][0][u] = (half_t)xrowB[u];
    if (u == 0) {
      xh[0][0][0][64] = (half_t)xrowA[64];
      xh[1][0][0][64] = (half_t)xrowB[64];
    }
    nA = xrowA[H + u];
    nB = xrowB[H + u];
    if (u == 0) { nA64 = xrowA[H + 64]; nB64 = xrowB[H + 64]; }
  }
  __syncthreads();

  float cstA = 0.f, cstB = 0.f;  // cell states (replicated across quad lanes)

  for (int s = 0; s <= T_STEPS; ++s) {
    const int p = s & 1;

    // distance-2 global prefetch (latency hidden across the step)
    float fA = 0.f, fA64 = 0.f, fB = 0.f, fB64 = 0.f;
    if (isW6 && (s + 2 < T_STEPS)) {
      const float* xrA = xrowA + (size_t)(s + 2) * H;
      const float* xrB = xrowB + (size_t)(s + 2) * H;
      fA = xrA[u];
      fB = xrB[u];
      if (u == 0) { fA64 = xrA[64]; fB64 = xrB[64]; }
    }

    const bool act = l ? (s >= 1) : (s < T_STEPS);
    if (act) {
      const half_t* xbA = &xh[0][l][p][0] + 72 * kh;
      const half_t* xbB = &xh[1][l][p][0] + 72 * kh;
      float a0A = hb[0], a1A = hb[1];
      float a0B = hb[0], a1B = hb[1];
#pragma unroll
      for (int c = 0; c < 8; ++c) {
        uint4 qA = ((const uint4*)xbA)[c];
        uint4 qB = ((const uint4*)xbB)[c];
        half2_t xA0 = __builtin_bit_cast(half2_t, qA.x);
        half2_t xA1 = __builtin_bit_cast(half2_t, qA.y);
        half2_t xA2 = __builtin_bit_cast(half2_t, qA.z);
        half2_t xA3 = __builtin_bit_cast(half2_t, qA.w);
        half2_t xB0 = __builtin_bit_cast(half2_t, qB.x);
        half2_t xB1 = __builtin_bit_cast(half2_t, qB.y);
        half2_t xB2 = __builtin_bit_cast(half2_t, qB.z);
        half2_t xB3 = __builtin_bit_cast(half2_t, qB.w);
        a0A = dot2(xA0, w[0][4 * c + 0], a0A);
        a0B = dot2(xB0, w[0][4 * c + 0], a0B);
        a1A = dot2(xA0, w[1][4 * c + 0], a1A);
        a1B = dot2(xB0, w[1][4 * c + 0], a1B);
        a0A = dot2(xA1, w[0][4 * c + 1], a0A);
        a0B = dot2(xB1, w[0][4 * c + 1], a0B);
        a1A = dot2(xA1, w[1][4 * c + 1], a1A);
        a1B = dot2(xB1, w[1][4 * c + 1], a1B);
        a0A = dot2(xA2, w[0][4 * c + 2], a0A);
        a0B = dot2(xB2, w[0][4 * c + 2], a0B);
        a1A = dot2(xA2, w[1][4 * c + 2], a1A);
        a1B = dot2(xB2, w[1][4 * c + 2], a1B);
        a0A = dot2(xA3, w[0][4 * c + 3], a0A);
        a0B = dot2(xB3, w[0][4 * c + 3], a0B);
        a1A = dot2(xA3, w[1][4 * c + 3], a1A);
        a1B = dot2(xB3, w[1][4 * c + 3], a1B);
      }
      {
        half2_t xtA = *(const half2_t*)(xbA + 64);  // tail pair (elem 64 + pad)
        half2_t xtB = *(const half2_t*)(xbB + 64);
        a0A = dot2(xtA, w[0][32], a0A);
        a0B = dot2(xtB, w[0][32], a0B);
        a1A = dot2(xtA, w[1][32], a1A);
        a1B = dot2(xtB, w[1][32], a1B);
      }
      a0A += qperm<0x4E>(a0A);  // K-combine with kh partner
      a1A += qperm<0x4E>(a1A);
      a0B += qperm<0x4E>(a0B);
      a1B += qperm<0x4E>(a1B);
      float e0A = fast_sigm(a0A);
      float e1A = mreg * fast_sigm(mreg * a1A) - msub;  // tanh via 2σ(2x)-1
      float e0B = fast_sigm(a0B);
      float e1B = mreg * fast_sigm(mreg * a1B) - msub;
      float p0A = qperm<0xB1>(e0A);  // gate-pair exchange
      float p1A = qperm<0xB1>(e1A);
      float p0B = qperm<0xB1>(e0B);
      float p1B = qperm<0xB1>(e1B);
      float ivA = gz ? e0A : p0A, fvA = gz ? p0A : e0A;
      float gvA = gz ? e1A : p1A, ovA = gz ? p1A : e1A;
      float ivB = gz ? e0B : p0B, fvB = gz ? p0B : e0B;
      float gvB = gz ? e1B : p1B, ovB = gz ? p1B : e1B;
      cstA = fvA * cstA + ivA * gvA;
      cstB = fvB * cstB + ivB * gvB;
      float thA = 2.f * fast_sigm(2.f * cstA) - 1.f;
      float thB = 2.f * fast_sigm(2.f * cstB) - 1.f;
      float hvA = ovA * thA;
      float hvB = ovB * thB;
      if ((tid & 3) == 0) {
        half_t hA = (half_t)hvA;
        half_t hB = (half_t)hvB;
        if (l == 0) {
          xh[0][0][p ^ 1][72 + j] = hA;  // own recurrence
          xh[0][1][p ^ 1][j]      = hA;  // layer-1 input
          xh[1][0][p ^ 1][72 + j] = hB;
          xh[1][1][p ^ 1][j]      = hB;
        } else {
          xh[0][1][p ^ 1][72 + j] = hA;
          xh[1][1][p ^ 1][72 + j] = hB;
          if (s == T_STEPS) { h1f[0][j] = hvA; h1f[1][j] = hvB; }
        }
      }
    }

    // ---- EC path (wave 7): columns (l=1, j=63,64), both rows ----
    if (isW7 && s >= 1) {
      const char* xbA1 = (const char*)&xh[0][1][p][0];
      const char* xbB1 = (const char*)&xh[1][1][p][0];
      float aecA = ecbias, aecB = ecbias;
#pragma unroll
      for (int i = 0; i < 9; ++i) {
        unsigned qA = *(const unsigned*)(xbA1 + ecoff + 4 * i);
        unsigned qB = *(const unsigned*)(xbB1 + ecoff + 4 * i);
        aecA = dot2(__builtin_bit_cast(half2_t, qA), ecw[i], aecA);
        aecB = dot2(__builtin_bit_cast(half2_t, qB), ecw[i], aecB);
      }
      aecA += swz<0x041F>(aecA);  // xor1
      aecB += swz<0x041F>(aecB);
      aecA += swz<0x081F>(aecA);  // xor2
      aecB += swz<0x081F>(aecB);
      aecA += swz<0x101F>(aecA);  // xor4: full column preact in all 8 lanes
      aecB += swz<0x101F>(aecB);
      const int gec = ec & 3;
      float me = (gec == 2) ? 2.f : 1.f;
      float AA = me * fast_sigm(me * aecA) - (me - 1.f);
      float AB = me * fast_sigm(me * aecB) - (me - 1.f);
      float BvA = swz<0x201F>(AA);   // act of ec^1
      float BvB = swz<0x201F>(AB);
      float CvA = swz<0x401F>(AA);   // act of ec^2
      float CvB = swz<0x401F>(AB);
      float DvA = swz<0x401F>(BvA);  // act of ec^3
      float DvB = swz<0x401F>(BvB);
      float ivA2 = pick(gec ^ 0, AA, BvA, CvA, DvA);
      float fvA2 = pick(gec ^ 1, AA, BvA, CvA, DvA);
      float gvA2 = pick(gec ^ 2, AA, BvA, CvA, DvA);
      float ovA2 = pick(gec ^ 3, AA, BvA, CvA, DvA);
      float ivB2 = pick(gec ^ 0, AB, BvB, CvB, DvB);
      float fvB2 = pick(gec ^ 1, AB, BvB, CvB, DvB);
      float gvB2 = pick(gec ^ 2, AB, BvB, CvB, DvB);
      float ovB2 = pick(gec ^ 3, AB, BvB, CvB, DvB);
      cecA = fvA2 * cecA + ivA2 * gvA2;
      cecB = fvB2 * cecB + ivB2 * gvB2;
      float hecA = ovA2 * (2.f * fast_sigm(2.f * cecA) - 1.f);
      float hecB = ovB2 * (2.f * fast_sigm(2.f * cecB) - 1.f);
      if (ck == 0 && (ec & 3) == 0) {  // w7==0 -> j63, w7==32 -> j64
        const int jec = 63 + (ec >> 2);
        xh[0][1][p ^ 1][72 + jec] = (half_t)hecA;
        xh[1][1][p ^ 1][72 + jec] = (half_t)hecB;
        if (s == T_STEPS) { h1f[0][jec] = hecA; h1f[1][jec] = hecB; }
      }
    }

    // stage x_{s+1} for both rows; shift prefetch pipeline
    if (isW6 && (s + 1 < T_STEPS)) {
      half_t* dA = &xh[0][0][p ^ 1][0];
      half_t* dB = &xh[1][0][p ^ 1][0];
      dA[u] = (half_t)nA;
      dB[u] = (half_t)nB;
      if (u == 0) { dA[64] = (half_t)nA64; dB[64] = (half_t)nB64; }
      nA = fA; nA64 = fA64; nB = fB; nB64 = fB64;
    }
    __syncthreads();
  }

  // ---- output projection: out[b] = b_lin + h1_final . w_lin ----
  if (tid == 0) {
    float acc0 = blin[0], acc1 = blin[0];
    for (int jj = 0; jj < H; ++jj) {
      acc0 += h1f[0][jj] * wlin[jj];
      acc1 += h1f[1][jj] * wlin[jj];
    }
    out[2 * blockIdx.x]     = acc0;
    out[2 * blockIdx.x + 1] = acc1;
  }
}

extern "C" void kernel_launch(void* const* d_in, const int* in_sizes, int n_in,
                              void* d_out, int out_size, void* d_ws, size_t ws_size,
                              hipStream_t stream) {
  const float* x    = (const float*)d_in[0];
  const float* wih0 = (const float*)d_in[1];
  const float* whh0 = (const float*)d_in[2];
  const float* bih0 = (const float*)d_in[3];
  const float* bhh0 = (const float*)d_in[4];
  const float* wih1 = (const float*)d_in[5];
  const float* whh1 = (const float*)d_in[6];
  const float* bih1 = (const float*)d_in[7];
  const float* bhh1 = (const float*)d_in[8];
  const float* wlin = (const float*)d_in[9];
  const float* blin = (const float*)d_in[10];
  float* out = (float*)d_out;

  lstm_fused<<<256, 512, 0, stream>>>(x, wih0, whh0, bih0, bhh0,
                                      wih1, whh1, bih1, bhh1, wlin, blin, out);
}

// Round 6
// 1435.738 us; speedup vs baseline: 1.0584x; 1.0584x over previous
//
#include <hip/hip_runtime.h>

#define H 65
#define T_STEPS 1024

typedef _Float16 half_t;
typedef _Float16 half2_t __attribute__((ext_vector_type(2)));

// Guaranteed v_dot2_f32_f16
static __device__ __forceinline__ float dot2(half2_t a, half2_t b, float c) {
#if __has_builtin(__builtin_amdgcn_fdot2)
  return __builtin_amdgcn_fdot2(a, b, c, false);
#else
  float d;
  asm("v_dot2_f32_f16 %0, %1, %2, %3" : "=v"(d) : "v"(a), "v"(b), "v"(c));
  return d;
#endif
}

// Quad-lane permute via DPP. 0xB1=[1,0,3,2] (xor1), 0x4E=[2,3,0,1] (xor2)
template <int CTRL>
static __device__ __forceinline__ float qperm(float v) {
  int r = __builtin_amdgcn_update_dpp(0, __builtin_bit_cast(int, v), CTRL, 0xF, 0xF, true);
  return __builtin_bit_cast(float, r);
}

// ds_swizzle BitMode: offset = (xor<<10)|(or<<5)|and(0x1F)
template <int PAT>
static __device__ __forceinline__ float swz(float v) {
  int r = __builtin_amdgcn_ds_swizzle(__builtin_bit_cast(int, v), PAT);
  return __builtin_bit_cast(float, r);
}

#define LOG2E 1.44269504089f
static __device__ __forceinline__ float fast_sigm(float v) {
  float e = __builtin_amdgcn_exp2f(-LOG2E * v);
  return __builtin_amdgcn_rcpf(1.f + e);
}

// select [a,b,c,d][idx], branchless
static __device__ __forceinline__ float pick(int idx, float a, float b, float c, float d) {
  float lo = (idx & 1) ? b : a;
  float hi = (idx & 1) ? d : c;
  return (idx & 2) ? hi : lo;
}

// ============================================================================
// KERNEL A: 1024 threads, 2 rows (waves 0..7 = row 2b, waves 8..15 = row 2b+1),
// r3's proven-correct structure. r3/r4 failed only because the compiler capped
// VGPRs at 64 (heuristic) and spilled the 66-reg weight cache (43-46 MB scratch
// traffic/launch). amdgpu_num_vgpr(120) requests the budget directly: a 1024t
// block is 16 waves = 4/SIMD, so 120 regs fits the 512-reg/SIMD file (4x120).
// Runtime dispatch (below) only uses this kernel if hipFuncGetAttributes shows
// it compiled spill-free with >70 regs; otherwise falls back to KERNEL B.
// ============================================================================
#if __has_attribute(amdgpu_num_vgpr)
#define VGPR_REQ __attribute__((amdgpu_num_vgpr(120)))
#else
#define VGPR_REQ
#endif

__global__
__attribute__((amdgpu_flat_work_group_size(1024, 1024)))
VGPR_REQ
void lstm_fused_1024(
    const float* __restrict__ x,
    const float* __restrict__ wih0, const float* __restrict__ whh0,
    const float* __restrict__ bih0, const float* __restrict__ bhh0,
    const float* __restrict__ wih1, const float* __restrict__ whh1,
    const float* __restrict__ bih1, const float* __restrict__ bhh1,
    const float* __restrict__ wlin, const float* __restrict__ blin,
    float* __restrict__ out)
{
  __shared__ __align__(16) half_t xh[2][2][2][144];
  __shared__ float h1f[2][H];

  const int tid = threadIdx.x;
  const int rr  = tid >> 9;        // row slot within block
  const int t5  = tid & 511;       // index within the 512t row-half
  const int b   = 2 * blockIdx.x + rr;

  const int quad = t5 >> 2;
  const int l  = (quad >= 65) ? 1 : 0;
  const int j  = quad - 65 * l;
  const int kh = (t5 >> 1) & 1;
  const int g0 = t5 & 1;
  const bool gz = (g0 == 0);
  const float mreg = gz ? 2.f : 1.f;
  const float msub = mreg - 1.f;

  half2_t w[2][33];
  float hb[2];
  {
    const float* wi = l ? wih1 : wih0;
    const float* wh = l ? whh1 : whh0;
    const float* bi = l ? bih1 : bih0;
    const float* bh = l ? bhh1 : bhh0;
#pragma unroll
    for (int cc = 0; cc < 2; ++cc) {
      const int row = (g0 + 2 * cc) * H + j;
      hb[cc] = 0.5f * (bi[row] + bh[row]);
      const float* src = (kh ? wh : wi) + row * H;
#pragma unroll
      for (int pp = 0; pp < 33; ++pp) {
        float e0 = src[2 * pp];
        float e1 = (2 * pp + 1 < H) ? src[2 * pp + 1] : 0.f;
        half2_t v = {(half_t)e0, (half_t)e1};
        w[cc][pp] = v;
      }
    }
  }

  const bool isW7 = (t5 >= 448);
  const int  w7   = t5 - 448;
  const int  ec   = w7 >> 3;
  const int  ck   = w7 & 7;
  const int  side = ck >> 2;
  const int  sck  = ck & 3;
  const int  ecoff = side * 144 + 36 * sck;
  half2_t ecw[9];
  float ecbias = 0.f;
  float cec = 0.f;
  if (isW7) {
    const int gec = ec & 3;
    const int jec = 63 + (ec >> 2);
    const int row = gec * H + jec;
    const float* src = (side ? whh1 : wih1) + row * H;
#pragma unroll
    for (int i = 0; i < 9; ++i) {
      int es = 9 * sck + i;
      float e0 = (es < 33) ? src[2 * es] : 0.f;
      float e1 = (es < 33 && 2 * es + 1 < H) ? src[2 * es + 1] : 0.f;
      half2_t v = {(half_t)e0, (half_t)e1};
      ecw[i] = v;
    }
    if (ck == 0) ecbias = bih1[row] + bhh1[row];
  } else {
#pragma unroll
    for (int i = 0; i < 9; ++i) {
      half2_t z = {(half_t)0.f, (half_t)0.f};
      ecw[i] = z;
    }
  }

  const bool isW6 = (t5 >= 384) && (t5 < 448);
  const int  u    = t5 - 384;

  for (int i = tid; i < 2 * 2 * 2 * 144; i += 1024) ((half_t*)xh)[i] = (half_t)0.f;
  __syncthreads();

  const float* xrow = x + (size_t)b * (size_t)(T_STEPS * H);
  float nxA = 0.f, nxB = 0.f;
  if (isW6) {
    xh[rr][0][0][u] = (half_t)xrow[u];
    if (u == 0) xh[rr][0][0][64] = (half_t)xrow[64];
    nxA = xrow[H + u];
    if (u == 0) nxB = xrow[H + 64];
  }
  __syncthreads();

  float cst = 0.f;

  for (int s = 0; s <= T_STEPS; ++s) {
    const int p = s & 1;

    float fA = 0.f, fB = 0.f;
    if (isW6 && (s + 2 < T_STEPS)) {
      const float* xr = xrow + (size_t)(s + 2) * H;
      fA = xr[u];
      if (u == 0) fB = xr[64];
    }

    const bool act = l ? (s >= 1) : (s < T_STEPS);
    if (act) {
      const half_t* xb = &xh[rr][l][p][0] + 72 * kh;
      float a0 = hb[0], a1 = hb[1];
#pragma unroll
      for (int c = 0; c < 8; ++c) {
        uint4 qv = ((const uint4*)xb)[c];
        half2_t x0 = __builtin_bit_cast(half2_t, qv.x);
        half2_t x1 = __builtin_bit_cast(half2_t, qv.y);
        half2_t x2 = __builtin_bit_cast(half2_t, qv.z);
        half2_t x3 = __builtin_bit_cast(half2_t, qv.w);
        a0 = dot2(x0, w[0][4 * c + 0], a0);
        a1 = dot2(x0, w[1][4 * c + 0], a1);
        a0 = dot2(x1, w[0][4 * c + 1], a0);
        a1 = dot2(x1, w[1][4 * c + 1], a1);
        a0 = dot2(x2, w[0][4 * c + 2], a0);
        a1 = dot2(x2, w[1][4 * c + 2], a1);
        a0 = dot2(x3, w[0][4 * c + 3], a0);
        a1 = dot2(x3, w[1][4 * c + 3], a1);
      }
      {
        half2_t xt = *(const half2_t*)(xb + 64);
        a0 = dot2(xt, w[0][32], a0);
        a1 = dot2(xt, w[1][32], a1);
      }
      a0 += qperm<0x4E>(a0);
      a1 += qperm<0x4E>(a1);
      float e0 = fast_sigm(a0);
      float e1 = mreg * fast_sigm(mreg * a1) - msub;
      float p0 = qperm<0xB1>(e0);
      float p1 = qperm<0xB1>(e1);
      float iv = gz ? e0 : p0;
      float fv = gz ? p0 : e0;
      float gv = gz ? e1 : p1;
      float ov = gz ? p1 : e1;
      cst = fv * cst + iv * gv;
      float th = 2.f * fast_sigm(2.f * cst) - 1.f;
      float hv = ov * th;
      if ((t5 & 3) == 0) {
        half_t hh = (half_t)hv;
        if (l == 0) {
          xh[rr][0][p ^ 1][72 + j] = hh;
          xh[rr][1][p ^ 1][j]      = hh;
        } else {
          xh[rr][1][p ^ 1][72 + j] = hh;
          if (s == T_STEPS) h1f[rr][j] = hv;
        }
      }
    }

    if (isW7 && s >= 1) {
      const char* xb1 = (const char*)&xh[rr][1][p][0];
      float aec = ecbias;
#pragma unroll
      for (int i = 0; i < 9; ++i) {
        unsigned qv = *(const unsigned*)(xb1 + ecoff + 4 * i);
        aec = dot2(__builtin_bit_cast(half2_t, qv), ecw[i], aec);
      }
      aec += swz<0x041F>(aec);
      aec += swz<0x081F>(aec);
      aec += swz<0x101F>(aec);
      const int gec = ec & 3;
      float me = (gec == 2) ? 2.f : 1.f;
      float A  = me * fast_sigm(me * aec) - (me - 1.f);
      float Bv = swz<0x201F>(A);
      float Cv = swz<0x401F>(A);
      float Dv = swz<0x401F>(Bv);
      float iv2 = pick(gec ^ 0, A, Bv, Cv, Dv);
      float fv2 = pick(gec ^ 1, A, Bv, Cv, Dv);
      float gv2 = pick(gec ^ 2, A, Bv, Cv, Dv);
      float ov2 = pick(gec ^ 3, A, Bv, Cv, Dv);
      cec = fv2 * cec + iv2 * gv2;
      float hec = ov2 * (2.f * fast_sigm(2.f * cec) - 1.f);
      if (ck == 0 && (ec & 3) == 0) {
        const int jec = 63 + (ec >> 2);
        xh[rr][1][p ^ 1][72 + jec] = (half_t)hec;
        if (s == T_STEPS) h1f[rr][jec] = hec;
      }
    }

    if (isW6 && (s + 1 < T_STEPS)) {
      half_t* dst = &xh[rr][0][p ^ 1][0];
      dst[u] = (half_t)nxA;
      if (u == 0) dst[64] = (half_t)nxB;
      nxA = fA; nxB = fB;
    }
    __syncthreads();
  }

  if (t5 == 0) {
    float acc = blin[0];
    for (int jj = 0; jj < H; ++jj) acc += h1f[rr][jj] * wlin[jj];
    out[b] = acc;
  }
}

// ============================================================================
// KERNEL B: fallback — r5's proven 512t / 2-rows-in-lane structure with:
//  - __launch_bounds__(512,1): 1 block/CU anyway (dispatcher refuses 2 blocks
//    at >64 regs, r1), so give the allocator the 256-reg budget for deeper
//    operand prefetch instead of pinning 128.
//  - wave balance: r5 stacked BOTH rows' EC on wave 7 (+~120 instrs on the
//    barrier-convoy critical wave). Now: x-staging on wave 0, EC row A on
//    wave 6, EC row B on wave 7.
// ============================================================================
__global__ __launch_bounds__(512, 1) void lstm_fused_512(
    const float* __restrict__ x,
    const float* __restrict__ wih0, const float* __restrict__ whh0,
    const float* __restrict__ bih0, const float* __restrict__ bhh0,
    const float* __restrict__ wih1, const float* __restrict__ whh1,
    const float* __restrict__ bih1, const float* __restrict__ bhh1,
    const float* __restrict__ wlin, const float* __restrict__ blin,
    float* __restrict__ out)
{
  __shared__ __align__(16) half_t xh[2][2][2][144];
  __shared__ float h1f[2][H];

  const int tid = threadIdx.x;

  const int quad = tid >> 2;
  const int l  = (quad >= 65) ? 1 : 0;
  const int j  = quad - 65 * l;
  const int kh = (tid >> 1) & 1;
  const int g0 = tid & 1;
  const bool gz = (g0 == 0);
  const float mreg = gz ? 2.f : 1.f;
  const float msub = mreg - 1.f;

  // ---- regular weights: shared by both rows ----
  half2_t w[2][33];
  float hb[2];
  {
    const float* wi = l ? wih1 : wih0;
    const float* wh = l ? whh1 : whh0;
    const float* bi = l ? bih1 : bih0;
    const float* bh = l ? bhh1 : bhh0;
#pragma unroll
    for (int cc = 0; cc < 2; ++cc) {
      const int row = (g0 + 2 * cc) * H + j;
      hb[cc] = 0.5f * (bi[row] + bh[row]);
      const float* src = (kh ? wh : wi) + row * H;
#pragma unroll
      for (int pp = 0; pp < 33; ++pp) {
        float e0 = src[2 * pp];
        float e1 = (2 * pp + 1 < H) ? src[2 * pp + 1] : 0.f;
        half2_t v = {(half_t)e0, (half_t)e1};
        w[cc][pp] = v;
      }
    }
  }

  // ---- EC: wave 6 handles row A, wave 7 handles row B (same role layout) ----
  const bool isEC = (tid >= 384);
  const int  e6   = tid & 63;
  const int  ecR  = (tid >> 6) & 1;  // 384..447 -> 0 (row A), 448..511 -> 1 (row B)
  const int  ec   = e6 >> 3;
  const int  ck   = e6 & 7;
  const int  side = ck >> 2;
  const int  sck  = ck & 3;
  const int  ecoff = side * 144 + 36 * sck;
  half2_t ecw[9];
  float ecbias = 0.f;
  float cec = 0.f;
  if (isEC) {
    const int gec = ec & 3;
    const int jec = 63 + (ec >> 2);
    const int row = gec * H + jec;
    const float* src = (side ? whh1 : wih1) + row * H;
#pragma unroll
    for (int i = 0; i < 9; ++i) {
      int es = 9 * sck + i;
      float e0 = (es < 33) ? src[2 * es] : 0.f;
      float e1 = (es < 33 && 2 * es + 1 < H) ? src[2 * es + 1] : 0.f;
      half2_t v = {(half_t)e0, (half_t)e1};
      ecw[i] = v;
    }
    if (ck == 0) ecbias = bih1[row] + bhh1[row];
  } else {
#pragma unroll
    for (int i = 0; i < 9; ++i) {
      half2_t z = {(half_t)0.f, (half_t)0.f};
      ecw[i] = z;
    }
  }

  // ---- loaders: wave 0 stages BOTH rows' x (distance-2 pipeline) ----
  const bool isST = (tid < 64);
  const int  u    = tid;

  for (int i = tid; i < 2 * 2 * 2 * 144; i += 512) ((half_t*)xh)[i] = (half_t)0.f;
  __syncthreads();

  const float* xrowA = x + (size_t)(2 * blockIdx.x)     * (size_t)(T_STEPS * H);
  const float* xrowB = x + (size_t)(2 * blockIdx.x + 1) * (size_t)(T_STEPS * H);
  float nA = 0.f, nA64 = 0.f, nB = 0.f, nB64 = 0.f;
  if (isST) {
    xh[0][0][0][u] = (half_t)xrowA[u];
    xh[1][0][0][u] = (half_t)xrowB[u];
    if (u == 0) {
      xh[0][0][0][64] = (half_t)xrowA[64];
      xh[1][0][0][64] = (half_t)xrowB[64];
    }
    nA = xrowA[H + u];
    nB = xrowB[H + u];
    if (u == 0) { nA64 = xrowA[H + 64]; nB64 = xrowB[H + 64]; }
  }
  __syncthreads();

  float cstA = 0.f, cstB = 0.f;

  for (int s = 0; s <= T_STEPS; ++s) {
    const int p = s & 1;

    float fA = 0.f, fA64 = 0.f, fB = 0.f, fB64 = 0.f;
    if (isST && (s + 2 < T_STEPS)) {
      const float* xrA = xrowA + (size_t)(s + 2) * H;
      const float* xrB = xrowB + (size_t)(s + 2) * H;
      fA = xrA[u];
      fB = xrB[u];
      if (u == 0) { fA64 = xrA[64]; fB64 = xrB[64]; }
    }

    const bool act = l ? (s >= 1) : (s < T_STEPS);
    if (act) {
      const half_t* xbA = &xh[0][l][p][0] + 72 * kh;
      const half_t* xbB = &xh[1][l][p][0] + 72 * kh;
      float a0A = hb[0], a1A = hb[1];
      float a0B = hb[0], a1B = hb[1];
#pragma unroll
      for (int c = 0; c < 8; ++c) {
        uint4 qA = ((const uint4*)xbA)[c];
        uint4 qB = ((const uint4*)xbB)[c];
        half2_t xA0 = __builtin_bit_cast(half2_t, qA.x);
        half2_t xA1 = __builtin_bit_cast(half2_t, qA.y);
        half2_t xA2 = __builtin_bit_cast(half2_t, qA.z);
        half2_t xA3 = __builtin_bit_cast(half2_t, qA.w);
        half2_t xB0 = __builtin_bit_cast(half2_t, qB.x);
        half2_t xB1 = __builtin_bit_cast(half2_t, qB.y);
        half2_t xB2 = __builtin_bit_cast(half2_t, qB.z);
        half2_t xB3 = __builtin_bit_cast(half2_t, qB.w);
        a0A = dot2(xA0, w[0][4 * c + 0], a0A);
        a0B = dot2(xB0, w[0][4 * c + 0], a0B);
        a1A = dot2(xA0, w[1][4 * c + 0], a1A);
        a1B = dot2(xB0, w[1][4 * c + 0], a1B);
        a0A = dot2(xA1, w[0][4 * c + 1], a0A);
        a0B = dot2(xB1, w[0][4 * c + 1], a0B);
        a1A = dot2(xA1, w[1][4 * c + 1], a1A);
        a1B = dot2(xB1, w[1][4 * c + 1], a1B);
        a0A = dot2(xA2, w[0][4 * c + 2], a0A);
        a0B = dot2(xB2, w[0][4 * c + 2], a0B);
        a1A = dot2(xA2, w[1][4 * c + 2], a1A);
        a1B = dot2(xB2, w[1][4 * c + 2], a1B);
        a0A = dot2(xA3, w[0][4 * c + 3], a0A);
        a0B = dot2(xB3, w[0][4 * c + 3], a0B);
        a1A = dot2(xA3, w[1][4 * c + 3], a1A);
        a1B = dot2(xB3, w[1][4 * c + 3], a1B);
      }
      {
        half2_t xtA = *(const half2_t*)(xbA + 64);
        half2_t xtB = *(const half2_t*)(xbB + 64);
        a0A = dot2(xtA, w[0][32], a0A);
        a0B = dot2(xtB, w[0][32], a0B);
        a1A = dot2(xtA, w[1][32], a1A);
        a1B = dot2(xtB, w[1][32], a1B);
      }
      a0A += qperm<0x4E>(a0A);
      a1A += qperm<0x4E>(a1A);
      a0B += qperm<0x4E>(a0B);
      a1B += qperm<0x4E>(a1B);
      float e0A = fast_sigm(a0A);
      float e1A = mreg * fast_sigm(mreg * a1A) - msub;
      float e0B = fast_sigm(a0B);
      float e1B = mreg * fast_sigm(mreg * a1B) - msub;
      float p0A = qperm<0xB1>(e0A);
      float p1A = qperm<0xB1>(e1A);
      float p0B = qperm<0xB1>(e0B);
      float p1B = qperm<0xB1>(e1B);
      float ivA = gz ? e0A : p0A, fvA = gz ? p0A : e0A;
      float gvA = gz ? e1A : p1A, ovA = gz ? p1A : e1A;
      float ivB = gz ? e0B : p0B, fvB = gz ? p0B : e0B;
      float gvB = gz ? e1B : p1B, ovB = gz ? p1B : e1B;
      cstA = fvA * cstA + ivA * gvA;
      cstB = fvB * cstB + ivB * gvB;
      float thA = 2.f * fast_sigm(2.f * cstA) - 1.f;
      float thB = 2.f * fast_sigm(2.f * cstB) - 1.f;
      float hvA = ovA * thA;
      float hvB = ovB * thB;
      if ((tid & 3) == 0) {
        half_t hA = (half_t)hvA;
        half_t hB = (half_t)hvB;
        if (l == 0) {
          xh[0][0][p ^ 1][72 + j] = hA;
          xh[0][1][p ^ 1][j]      = hA;
          xh[1][0][p ^ 1][72 + j] = hB;
          xh[1][1][p ^ 1][j]      = hB;
        } else {
          xh[0][1][p ^ 1][72 + j] = hA;
          xh[1][1][p ^ 1][72 + j] = hB;
          if (s == T_STEPS) { h1f[0][j] = hvA; h1f[1][j] = hvB; }
        }
      }
    }

    // ---- EC path: wave 6 -> row A, wave 7 -> row B ----
    if (isEC && s >= 1) {
      const char* xb1 = (const char*)&xh[ecR][1][p][0];
      float aec = ecbias;
#pragma unroll
      for (int i = 0; i < 9; ++i) {
        unsigned qv = *(const unsigned*)(xb1 + ecoff + 4 * i);
        aec = dot2(__builtin_bit_cast(half2_t, qv), ecw[i], aec);
      }
      aec += swz<0x041F>(aec);
      aec += swz<0x081F>(aec);
      aec += swz<0x101F>(aec);
      const int gec = ec & 3;
      float me = (gec == 2) ? 2.f : 1.f;
      float A  = me * fast_sigm(me * aec) - (me - 1.f);
      float Bv = swz<0x201F>(A);
      float Cv = swz<0x401F>(A);
      float Dv = swz<0x401F>(Bv);
      float iv2 = pick(gec ^ 0, A, Bv, Cv, Dv);
      float fv2 = pick(gec ^ 1, A, Bv, Cv, Dv);
      float gv2 = pick(gec ^ 2, A, Bv, Cv, Dv);
      float ov2 = pick(gec ^ 3, A, Bv, Cv, Dv);
      cec = fv2 * cec + iv2 * gv2;
      float hec = ov2 * (2.f * fast_sigm(2.f * cec) - 1.f);
      if (ck == 0 && (ec & 3) == 0) {
        const int jec = 63 + (ec >> 2);
        xh[ecR][1][p ^ 1][72 + jec] = (half_t)hec;
        if (s == T_STEPS) h1f[ecR][jec] = hec;
      }
    }

    // stage x_{s+1} for both rows; shift prefetch pipeline
    if (isST && (s + 1 < T_STEPS)) {
      half_t* dA = &xh[0][0][p ^ 1][0];
      half_t* dB = &xh[1][0][p ^ 1][0];
      dA[u] = (half_t)nA;
      dB[u] = (half_t)nB;
      if (u == 0) { dA[64] = (half_t)nA64; dB[64] = (half_t)nB64; }
      nA = fA; nA64 = fA64; nB = fB; nB64 = fB64;
    }
    __syncthreads();
  }

  if (tid == 0) {
    float acc0 = blin[0], acc1 = blin[0];
    for (int jj = 0; jj < H; ++jj) {
      acc0 += h1f[0][jj] * wlin[jj];
      acc1 += h1f[1][jj] * wlin[jj];
    }
    out[2 * blockIdx.x]     = acc0;
    out[2 * blockIdx.x + 1] = acc1;
  }
}

extern "C" void kernel_launch(void* const* d_in, const int* in_sizes, int n_in,
                              void* d_out, int out_size, void* d_ws, size_t ws_size,
                              hipStream_t stream) {
  const float* x    = (const float*)d_in[0];
  const float* wih0 = (const float*)d_in[1];
  const float* whh0 = (const float*)d_in[2];
  const float* bih0 = (const float*)d_in[3];
  const float* bhh0 = (const float*)d_in[4];
  const float* wih1 = (const float*)d_in[5];
  const float* whh1 = (const float*)d_in[6];
  const float* bih1 = (const float*)d_in[7];
  const float* bhh1 = (const float*)d_in[8];
  const float* wlin = (const float*)d_in[9];
  const float* blin = (const float*)d_in[10];
  float* out = (float*)d_out;

  // One-time host-side dispatch: use the 1024t kernel only if the compiler
  // actually honored the VGPR request (spill-free, weight cache in regs).
  static int use1024 = -1;
  if (use1024 < 0) {
    hipFuncAttributes a{};
    if (hipFuncGetAttributes(&a, reinterpret_cast<const void*>(&lstm_fused_1024)) == hipSuccess &&
        a.localSizeBytes == 0 && a.numRegs > 70) {
      use1024 = 1;
    } else {
      use1024 = 0;
    }
  }

  if (use1024) {
    lstm_fused_1024<<<256, 1024, 0, stream>>>(x, wih0, whh0, bih0, bhh0,
                                              wih1, whh1, bih1, bhh1, wlin, blin, out);
  } else {
    lstm_fused_512<<<256, 512, 0, stream>>>(x, wih0, whh0, bih0, bhh0,
                                            wih1, whh1, bih1, bhh1, wlin, blin, out);
  }
}